// Round 1
// baseline (6404.004 us; speedup 1.0000x reference)
//
#include <hip/hip_runtime.h>
#include <math.h>

// RipsLayer: dim-0 persistence of Rips filtration on 4096 points in R^64.
// Phase 1: dense distance matrix D (64 MiB, in d_ws).
// Phase 2: exact Prim replay, 1 workgroup / 4 waves:
//   - DPP (row_shr/row_bcast) wave min-reduce + ballot index recovery
//     (blocked col ownership -> lowest lane == lowest col, exact ties)
//   - two-phase m1/m2 argmin: m1 over mind hides the row-j load latency
//   - tree membership encoded as mind==INF (no mask bitfield)
//   - NEW: speculative runner-up prefetch. Each iter posts BOTH per-wave
//     keys (m1,m2) to LDS; after the barrier we compute the exact winner j
//     AND an approximate global runner-up (min over the 8 keys with
//     col != j). Its row is prefetched into a spare register bank. Next
//     iter, if the exactly-selected j matches the prediction, the row has
//     been in flight ~2 iterations -> zero exposed load latency; else we
//     fall back to the exact fresh-load path. Selection semantics are
//     untouched, so correctness never depends on the predictor.

#define N 4096
#define DF 64
#define INF __builtin_huge_valf()
#define INFBITS 0x7f800000u

// ---------------------------------------------------------------------------
// Phase 1: D[i][j] = sqrt(max(|x_i - x_j|^2, 1e-12)), diag = +inf.
// ---------------------------------------------------------------------------
__global__ __launch_bounds__(256) void build_d_kernel(const float* __restrict__ x,
                                                      float* __restrict__ D) {
    __shared__ float As[64][68];
    __shared__ float Bs[64][68];
    const int bi = blockIdx.y * 64;
    const int bj = blockIdx.x * 64;
    const int t = threadIdx.x;

#pragma unroll
    for (int g = 0; g < 4; ++g) {
        int idx = t + 256 * g;
        int row = idx >> 4;
        int k4 = (idx & 15) << 2;
        float4 va = *(const float4*)(x + (size_t)(bi + row) * DF + k4);
        float4 vb = *(const float4*)(x + (size_t)(bj + row) * DF + k4);
        *(float4*)(&As[row][k4]) = va;
        *(float4*)(&Bs[row][k4]) = vb;
    }
    __syncthreads();

    const int ti = (t >> 4) << 2;
    const int tj = (t & 15) << 2;

    float acc[4][4];
#pragma unroll
    for (int r = 0; r < 4; ++r)
#pragma unroll
        for (int c = 0; c < 4; ++c) acc[r][c] = 0.0f;

    for (int k = 0; k < 64; k += 4) {
        float4 a[4], b[4];
#pragma unroll
        for (int r = 0; r < 4; ++r) a[r] = *(const float4*)(&As[ti + r][k]);
#pragma unroll
        for (int c = 0; c < 4; ++c) b[c] = *(const float4*)(&Bs[tj + c][k]);
#pragma unroll
        for (int r = 0; r < 4; ++r)
#pragma unroll
            for (int c = 0; c < 4; ++c) {
                float d0 = a[r].x - b[c].x;
                float d1 = a[r].y - b[c].y;
                float d2 = a[r].z - b[c].z;
                float d3 = a[r].w - b[c].w;
                float s = acc[r][c];
                s = fmaf(d0, d0, s);
                s = fmaf(d1, d1, s);
                s = fmaf(d2, d2, s);
                s = fmaf(d3, d3, s);
                acc[r][c] = s;
            }
    }

#pragma unroll
    for (int r = 0; r < 4; ++r) {
        int i = bi + ti + r;
        float4 v;
        float* vp = &v.x;
#pragma unroll
        for (int c = 0; c < 4; ++c) {
            int j = bj + tj + c;
            vp[c] = (i == j) ? INF : sqrtf(fmaxf(acc[r][c], 1e-12f));
        }
        *(float4*)(D + (size_t)i * N + (bj + tj)) = v;
    }
}

// ---------------------------------------------------------------------------
// Barrier that publishes LDS (lgkmcnt) but leaves global loads in flight.
// ---------------------------------------------------------------------------
__device__ __forceinline__ void barrier_no_drain() {
    __asm__ __volatile__("s_waitcnt lgkmcnt(0)\n\ts_barrier" ::: "memory");
}

// ---------------------------------------------------------------------------
// Wave64 min via DPP: row_shr 1/2/4/8 then row_bcast 15/31; result in lane 63.
// update_dpp(old=INF,...) makes invalid source lanes contribute identity.
// ---------------------------------------------------------------------------
#define DPP_MIN_STEP(x, ctrl)                                                  \
    x = fminf(x, __int_as_float(__builtin_amdgcn_update_dpp(                   \
                     0x7f800000, __float_as_int(x), ctrl, 0xF, 0xF, false)))

__device__ __forceinline__ float wave_min_f32_l63(float x) {
    DPP_MIN_STEP(x, 0x111);  // row_shr:1
    DPP_MIN_STEP(x, 0x112);  // row_shr:2
    DPP_MIN_STEP(x, 0x114);  // row_shr:4
    DPP_MIN_STEP(x, 0x118);  // row_shr:8
    DPP_MIN_STEP(x, 0x142);  // row_bcast:15
    DPP_MIN_STEP(x, 0x143);  // row_bcast:31
    return x;                // lane 63 = wave min
}

// lv/lcol: this lane's local min value and its (lowest) column. Ownership is
// blocked (lane owns cols [16t,16t+16)), so among tied lanes the lowest lane
// holds the lowest column -> exact jnp.argmin first-index semantics.
__device__ __forceinline__ unsigned long long wave_argmin_key(float lv, int lcol) {
    float red = wave_min_f32_l63(lv);
    float wm = __int_as_float(__builtin_amdgcn_readlane(__float_as_int(red), 63));
    unsigned long long tied = __ballot(lv == wm);
    int src = __ffsll(tied) - 1;
    int wcol = __builtin_amdgcn_readlane(lcol, src);
    return ((unsigned long long)__float_as_uint(wm) << 32) | (unsigned)wcol;
}

// Local argmin over 16 values with exact lowest-index tie-break.
__device__ __forceinline__ void local_argmin16(const float* __restrict__ a,
                                               float& bv, int& bi) {
    float v[16];
    int id[16];
#pragma unroll
    for (int i = 0; i < 16; ++i) { v[i] = a[i]; id[i] = i; }
#pragma unroll
    for (int st = 1; st < 16; st <<= 1)
#pragma unroll
        for (int i = 0; i < 16; i += 2 * st)
            if (v[i + st] < v[i]) {  // strict: keep lower index on ties
                v[i] = v[i + st];
                id[i] = id[i + st];
            }
    bv = v[0];
    bi = id[0];
}

// ---------------------------------------------------------------------------
// Phase 2. Invariant: mv[i] == INF  <=>  col (16t+i) is in the tree.
// ---------------------------------------------------------------------------
__global__ __launch_bounds__(256) void prim_kernel(const float* __restrict__ D,
                                                   float* __restrict__ out) {
    __shared__ __align__(16) unsigned long long part[2][4][2];
    const int t = threadIdx.x;
    const int lane = t & 63;
    const int wv = t >> 6;

    float mv[16];  // mind, pinned INF at tree cols
    float rv[16];  // row of last-selected vertex (in flight across backedge)
    float sv[16];  // speculative runner-up row (prefetch bank)
    {
        const float4* rp0 = (const float4*)(D + 16 * t);  // row 0; D[0][0]=INF
#pragma unroll
        for (int q = 0; q < 4; ++q) {
            float4 a = rp0[q];
            mv[4 * q + 0] = a.x; mv[4 * q + 1] = a.y;
            mv[4 * q + 2] = a.z; mv[4 * q + 3] = a.w;
        }
#pragma unroll
        for (int i = 0; i < 16; ++i) rv[i] = mv[i];  // "row of vertex 0"
#pragma unroll
        for (int i = 0; i < 16; ++i) sv[i] = 0.0f;
    }
    int scol = -1;  // column whose row is in flight in sv (-1 = none)

#pragma unroll 1
    for (int s = 1; s < N; ++s) {
        // ---- m1: argmin over mind (no dependence on the in-flight row) ----
        float bv1;
        int bi1;
        local_argmin16(mv, bv1, bi1);
        unsigned long long key1 = wave_argmin_key(bv1, 16 * t + bi1);

        // ---- m2: argmin over the arrived row, tree cols masked to INF ----
        float mr[16];
#pragma unroll
        for (int i = 0; i < 16; ++i)
            mr[i] = (__float_as_uint(mv[i]) == INFBITS) ? INF : rv[i];
        float bv2;
        int bi2;
        local_argmin16(mr, bv2, bi2);
        unsigned long long key2 = wave_argmin_key(bv2, 16 * t + bi2);

        // ---- post BOTH per-wave keys; exact winner + approx runner-up ----
        const int pb = s & 1;
        if (lane == 0) {
            ulonglong2 kk;
            kk.x = key1;
            kk.y = key2;
            *(ulonglong2*)&part[pb][wv][0] = kk;
        }
        barrier_no_drain();

        const ulonglong2* pp = (const ulonglong2*)&part[pb][0][0];
        ulonglong2 q0 = pp[0], q1 = pp[1], q2 = pp[2], q3 = pp[3];
        unsigned long long k0 = q0.x, k1 = q0.y, k2 = q1.x, k3 = q1.y;
        unsigned long long k4 = q2.x, k5 = q2.y, k6 = q3.x, k7 = q3.y;
        unsigned long long a0 = k0 < k1 ? k0 : k1;
        unsigned long long a1 = k2 < k3 ? k2 : k3;
        unsigned long long a2 = k4 < k5 ? k4 : k5;
        unsigned long long a3 = k6 < k7 ? k6 : k7;
        unsigned long long b0 = a0 < a1 ? a0 : a1;
        unsigned long long b1 = a2 < a3 ? a2 : a3;
        unsigned long long best = b0 < b1 ? b0 : b1;
        int j = __builtin_amdgcn_readfirstlane((int)(best & 0xffffffffULL));
        int dbits = __builtin_amdgcn_readfirstlane((int)(best >> 32));

        // runner-up = min over posted keys whose col != winner col
        unsigned bl = (unsigned)best;
        unsigned long long r0 = ((unsigned)k0 == bl) ? ~0ULL : k0;
        unsigned long long r1 = ((unsigned)k1 == bl) ? ~0ULL : k1;
        unsigned long long r2 = ((unsigned)k2 == bl) ? ~0ULL : k2;
        unsigned long long r3 = ((unsigned)k3 == bl) ? ~0ULL : k3;
        unsigned long long r4 = ((unsigned)k4 == bl) ? ~0ULL : k4;
        unsigned long long r5 = ((unsigned)k5 == bl) ? ~0ULL : k5;
        unsigned long long r6 = ((unsigned)k6 == bl) ? ~0ULL : k6;
        unsigned long long r7 = ((unsigned)k7 == bl) ? ~0ULL : k7;
        unsigned long long c0 = r0 < r1 ? r0 : r1;
        unsigned long long c1 = r2 < r3 ? r2 : r3;
        unsigned long long c2 = r4 < r5 ? r4 : r5;
        unsigned long long c3 = r6 < r7 ? r6 : r7;
        unsigned long long d0 = c0 < c1 ? c0 : c1;
        unsigned long long d1 = c2 < c3 ? c2 : c3;
        unsigned long long runner = d0 < d1 ? d0 : d1;
        int rcol = __builtin_amdgcn_readfirstlane((int)((unsigned)runner & (N - 1)));

        const bool hit = (j == scol);  // exact check; predictor only a hint

        // ---- row j for next iter: already in flight in sv on a hit ----
        if (!hit) {
            const float4* rp = (const float4*)(D + (size_t)(unsigned)j * N + 16 * t);
            float4 n0 = rp[0], n1 = rp[1], n2 = rp[2], n3 = rp[3];
            rv[0] = n0.x;  rv[1] = n0.y;  rv[2] = n0.z;  rv[3] = n0.w;
            rv[4] = n1.x;  rv[5] = n1.y;  rv[6] = n1.z;  rv[7] = n1.w;
            rv[8] = n2.x;  rv[9] = n2.y;  rv[10] = n2.z; rv[11] = n2.w;
            rv[12] = n3.x; rv[13] = n3.y; rv[14] = n3.z; rv[15] = n3.w;
        } else {
            // sv's load is >= 1 full iteration old -> wait here is ~free.
#pragma unroll
            for (int i = 0; i < 16; ++i) rv[i] = sv[i];
        }

        // ---- issue speculative prefetch of the runner-up's row ----
        {
            const float4* sp = (const float4*)(D + (size_t)(unsigned)rcol * N + 16 * t);
            float4 s0 = sp[0], s1 = sp[1], s2 = sp[2], s3 = sp[3];
            sv[0] = s0.x;  sv[1] = s0.y;  sv[2] = s0.z;  sv[3] = s0.w;
            sv[4] = s1.x;  sv[5] = s1.y;  sv[6] = s1.z;  sv[7] = s1.w;
            sv[8] = s2.x;  sv[9] = s2.y;  sv[10] = s2.z; sv[11] = s2.w;
            sv[12] = s3.x; sv[13] = s3.y; sv[14] = s3.z; sv[15] = s3.w;
        }
        scol = rcol;

        if (t == 0) {
            out[2 * (s - 1)] = 0.0f;
            out[2 * (s - 1) + 1] = __uint_as_float((unsigned)dbits);
        }

        // ---- fold (mind = min(mind, maskedR)) + pin newly-added col j ----
        unsigned jl = (unsigned)j & 15u;
        unsigned jt = (unsigned)j >> 4;
        bool mine = ((unsigned)t == jt);
#pragma unroll
        for (int i = 0; i < 16; ++i) {
            float m = fminf(mv[i], mr[i]);
            mv[i] = (mine && ((unsigned)i == jl)) ? INF : m;
        }
    }
}

// ---------------------------------------------------------------------------
extern "C" void kernel_launch(void* const* d_in, const int* in_sizes, int n_in,
                              void* d_out, int out_size, void* d_ws, size_t ws_size,
                              hipStream_t stream) {
    const float* x = (const float*)d_in[0];
    float* D = (float*)d_ws;     // requires ws_size >= N*N*4 = 64 MiB
    float* out = (float*)d_out;  // [N-1][2]: (birth=0, death)

    dim3 grid(N / 64, N / 64);
    build_d_kernel<<<grid, 256, 0, stream>>>(x, D);
    prim_kernel<<<1, 256, 0, stream>>>(D, out);
}

// Round 3
// 4771.884 us; speedup vs baseline: 1.3420x; 1.3420x over previous
//
#include <hip/hip_runtime.h>
#include <math.h>

// RipsLayer: dim-0 persistence of Rips filtration on 4096 points in R^64.
// Phase 1: dense distance matrix D (64 MiB, in d_ws).
// Phase 2: exact Prim replay, 1 workgroup / 4 waves:
//   - DPP (row_shr/row_bcast) wave min-reduce + ballot index recovery
//     (blocked col ownership -> lowest lane == lowest col, exact ties)
//   - two-phase m1/m2 argmin: m1 over mind hides the row-j load latency;
//     straight-line loop (no spec branches) so vmcnt waits land late
//   - tree membership encoded as mind==INF (no mask bitfield)
//   - NEW (vs 4030us baseline): L2-warming prefetch of the exact runner-up
//     candidate's row via global_load_lds into a never-read LDS scratch
//     buffer. Unlike R1 (register double-buffer -> WAW vmcnt drains) and
//     R2 (dead-VGPR hidden load -> delayed register write-back clobbered a
//     reused register -> GPU fault), global_load_lds has NO VGPR
//     destination: no write-back hazard, fully tracked by vmcnt so all
//     compiler waits stay correct. Selection semantics and rv register
//     flow identical to the 4030us baseline.

#define N 4096
#define DF 64
#define INF __builtin_huge_valf()
#define INFBITS 0x7f800000u

// ---------------------------------------------------------------------------
// Phase 1: D[i][j] = sqrt(max(|x_i - x_j|^2, 1e-12)), diag = +inf.
// ---------------------------------------------------------------------------
__global__ __launch_bounds__(256) void build_d_kernel(const float* __restrict__ x,
                                                      float* __restrict__ D) {
    __shared__ float As[64][68];
    __shared__ float Bs[64][68];
    const int bi = blockIdx.y * 64;
    const int bj = blockIdx.x * 64;
    const int t = threadIdx.x;

#pragma unroll
    for (int g = 0; g < 4; ++g) {
        int idx = t + 256 * g;
        int row = idx >> 4;
        int k4 = (idx & 15) << 2;
        float4 va = *(const float4*)(x + (size_t)(bi + row) * DF + k4);
        float4 vb = *(const float4*)(x + (size_t)(bj + row) * DF + k4);
        *(float4*)(&As[row][k4]) = va;
        *(float4*)(&Bs[row][k4]) = vb;
    }
    __syncthreads();

    const int ti = (t >> 4) << 2;
    const int tj = (t & 15) << 2;

    float acc[4][4];
#pragma unroll
    for (int r = 0; r < 4; ++r)
#pragma unroll
        for (int c = 0; c < 4; ++c) acc[r][c] = 0.0f;

    for (int k = 0; k < 64; k += 4) {
        float4 a[4], b[4];
#pragma unroll
        for (int r = 0; r < 4; ++r) a[r] = *(const float4*)(&As[ti + r][k]);
#pragma unroll
        for (int c = 0; c < 4; ++c) b[c] = *(const float4*)(&Bs[tj + c][k]);
#pragma unroll
        for (int r = 0; r < 4; ++r)
#pragma unroll
            for (int c = 0; c < 4; ++c) {
                float d0 = a[r].x - b[c].x;
                float d1 = a[r].y - b[c].y;
                float d2 = a[r].z - b[c].z;
                float d3 = a[r].w - b[c].w;
                float s = acc[r][c];
                s = fmaf(d0, d0, s);
                s = fmaf(d1, d1, s);
                s = fmaf(d2, d2, s);
                s = fmaf(d3, d3, s);
                acc[r][c] = s;
            }
    }

#pragma unroll
    for (int r = 0; r < 4; ++r) {
        int i = bi + ti + r;
        float4 v;
        float* vp = &v.x;
#pragma unroll
        for (int c = 0; c < 4; ++c) {
            int j = bj + tj + c;
            vp[c] = (i == j) ? INF : sqrtf(fmaxf(acc[r][c], 1e-12f));
        }
        *(float4*)(D + (size_t)i * N + (bj + tj)) = v;
    }
}

// ---------------------------------------------------------------------------
// Barrier that publishes LDS (lgkmcnt) but leaves global loads in flight.
// ---------------------------------------------------------------------------
__device__ __forceinline__ void barrier_no_drain() {
    __asm__ __volatile__("s_waitcnt lgkmcnt(0)\n\ts_barrier" ::: "memory");
}

// ---------------------------------------------------------------------------
// Wave64 min via DPP: row_shr 1/2/4/8 then row_bcast 15/31; result in lane 63.
// update_dpp(old=INF,...) makes invalid source lanes contribute identity.
// ---------------------------------------------------------------------------
#define DPP_MIN_STEP(x, ctrl)                                                  \
    x = fminf(x, __int_as_float(__builtin_amdgcn_update_dpp(                   \
                     0x7f800000, __float_as_int(x), ctrl, 0xF, 0xF, false)))

__device__ __forceinline__ float wave_min_f32_l63(float x) {
    DPP_MIN_STEP(x, 0x111);  // row_shr:1
    DPP_MIN_STEP(x, 0x112);  // row_shr:2
    DPP_MIN_STEP(x, 0x114);  // row_shr:4
    DPP_MIN_STEP(x, 0x118);  // row_shr:8
    DPP_MIN_STEP(x, 0x142);  // row_bcast:15
    DPP_MIN_STEP(x, 0x143);  // row_bcast:31
    return x;                // lane 63 = wave min
}

// lv/lcol: this lane's local min value and its (lowest) column. Ownership is
// blocked (lane owns cols [16t,16t+16)), so among tied lanes the lowest lane
// holds the lowest column -> exact jnp.argmin first-index semantics.
__device__ __forceinline__ unsigned long long wave_argmin_key(float lv, int lcol) {
    float red = wave_min_f32_l63(lv);
    float wm = __int_as_float(__builtin_amdgcn_readlane(__float_as_int(red), 63));
    unsigned long long tied = __ballot(lv == wm);
    int src = __ffsll(tied) - 1;
    int wcol = __builtin_amdgcn_readlane(lcol, src);
    return ((unsigned long long)__float_as_uint(wm) << 32) | (unsigned)wcol;
}

// Local argmin over 16 values with exact lowest-index tie-break.
__device__ __forceinline__ void local_argmin16(const float* __restrict__ a,
                                               float& bv, int& bi) {
    float v[16];
    int id[16];
#pragma unroll
    for (int i = 0; i < 16; ++i) { v[i] = a[i]; id[i] = i; }
#pragma unroll
    for (int st = 1; st < 16; st <<= 1)
#pragma unroll
        for (int i = 0; i < 16; i += 2 * st)
            if (v[i + st] < v[i]) {  // strict: keep lower index on ties
                v[i] = v[i + st];
                id[i] = id[i + st];
            }
    bv = v[0];
    bi = id[0];
}

// ---------------------------------------------------------------------------
// Phase 2. Invariant: mv[i] == INF  <=>  col (16t+i) is in the tree.
// ---------------------------------------------------------------------------
__global__ __launch_bounds__(256) void prim_kernel(const float* __restrict__ D,
                                                   float* __restrict__ out) {
    __shared__ __align__(16) unsigned long long part[2][4][2];
    __shared__ __align__(16) float junk[4][64];  // prefetch sink, never read
    const int t = threadIdx.x;
    const int lane = t & 63;
    const int wv = t >> 6;

    float mv[16];  // mind, pinned INF at tree cols
    float rv[16];  // row of last-selected vertex (in flight across backedge)
    {
        const float4* rp0 = (const float4*)(D + 16 * t);  // row 0; D[0][0]=INF
#pragma unroll
        for (int q = 0; q < 4; ++q) {
            float4 a = rp0[q];
            mv[4 * q + 0] = a.x; mv[4 * q + 1] = a.y;
            mv[4 * q + 2] = a.z; mv[4 * q + 3] = a.w;
        }
#pragma unroll
        for (int i = 0; i < 16; ++i) rv[i] = mv[i];  // "row of vertex 0"
    }

#pragma unroll 1
    for (int s = 1; s < N; ++s) {
        // ---- m1: argmin over mind (no dependence on the in-flight row) ----
        float bv1;
        int bi1;
        local_argmin16(mv, bv1, bi1);
        unsigned long long key1 = wave_argmin_key(bv1, 16 * t + bi1);

        // ---- m2: argmin over the arrived row, tree cols masked to INF ----
        float mr[16];
#pragma unroll
        for (int i = 0; i < 16; ++i)
            mr[i] = (__float_as_uint(mv[i]) == INFBITS) ? INF : rv[i];
        float bv2;
        int bi2;
        local_argmin16(mr, bv2, bi2);
        unsigned long long key2 = wave_argmin_key(bv2, 16 * t + bi2);

        // ---- post per-wave {min,max} keys ----
        unsigned long long kw = key1 < key2 ? key1 : key2;
        unsigned long long ko = key1 < key2 ? key2 : key1;
        const int pb = s & 1;
        if (lane == 0) {
            ulonglong2 kk;
            kk.x = kw;
            kk.y = ko;
            *(ulonglong2*)&part[pb][wv][0] = kk;
        }
        barrier_no_drain();

        const ulonglong2* pp = (const ulonglong2*)&part[pb][0][0];
        ulonglong2 p0 = pp[0], p1 = pp[1], p2 = pp[2], p3 = pp[3];
        unsigned long long b0 = p0.x < p1.x ? p0.x : p1.x;
        unsigned long long b1 = p2.x < p3.x ? p2.x : p3.x;
        unsigned long long best = b0 < b1 ? b0 : b1;
        int j = __builtin_amdgcn_readfirstlane((int)(best & 0xffffffffULL));
        int dbits = __builtin_amdgcn_readfirstlane((int)(best >> 32));

        // ---- issue next row load immediately (consumed next iter in m2) ----
        const float4* rp = (const float4*)(D + (size_t)(unsigned)j * N + 16 * t);
        float4 n0 = rp[0], n1 = rp[1], n2 = rp[2], n3 = rp[3];

        if (t == 0) {
            out[2 * (s - 1)] = 0.0f;
            out[2 * (s - 1) + 1] = __uint_as_float((unsigned)dbits);
        }

        // ---- off-path: exact runner-up of the 8 keys; warm its row in L2.
        // 2nd-best = min over (other waves' mins) U (winner wave's partner).
        // Cols are disjoint across waves -> exactly one p_i.x == best.
        // Prefetch dest is LDS (never read): no VGPR write-back hazard.
        {
            unsigned long long r0 = (p0.x == best) ? p0.y : p0.x;
            unsigned long long r1 = (p1.x == best) ? p1.y : p1.x;
            unsigned long long r2 = (p2.x == best) ? p2.y : p2.x;
            unsigned long long r3 = (p3.x == best) ? p3.y : p3.x;
            unsigned long long c0 = r0 < r1 ? r0 : r1;
            unsigned long long c1 = r2 < r3 ? r2 : r3;
            unsigned long long run = c0 < c1 ? c0 : c1;
            int rcol = (int)((unsigned)run & (N - 1));
            // 256 lanes x 4B at 64B stride cover the whole 16KB row's lines.
            const float* sp = D + (size_t)(unsigned)rcol * N + 16 * t;
            __builtin_amdgcn_global_load_lds(
                (const __attribute__((address_space(1))) void*)sp,
                (__attribute__((address_space(3))) void*)&junk[wv][0],
                4, 0, 0);
        }

        // ---- fold (mind = min(mind, maskedR)) + pin newly-added col j ----
        unsigned jl = (unsigned)j & 15u;
        unsigned jt = (unsigned)j >> 4;
        bool mine = ((unsigned)t == jt);
#pragma unroll
        for (int i = 0; i < 16; ++i) {
            float m = fminf(mv[i], mr[i]);
            mv[i] = (mine && ((unsigned)i == jl)) ? INF : m;
        }

        // ---- carry the new row ----
        rv[0] = n0.x;  rv[1] = n0.y;  rv[2] = n0.z;  rv[3] = n0.w;
        rv[4] = n1.x;  rv[5] = n1.y;  rv[6] = n1.z;  rv[7] = n1.w;
        rv[8] = n2.x;  rv[9] = n2.y;  rv[10] = n2.z; rv[11] = n2.w;
        rv[12] = n3.x; rv[13] = n3.y; rv[14] = n3.z; rv[15] = n3.w;
    }
}

// ---------------------------------------------------------------------------
extern "C" void kernel_launch(void* const* d_in, const int* in_sizes, int n_in,
                              void* d_out, int out_size, void* d_ws, size_t ws_size,
                              hipStream_t stream) {
    const float* x = (const float*)d_in[0];
    float* D = (float*)d_ws;     // requires ws_size >= N*N*4 = 64 MiB
    float* out = (float*)d_out;  // [N-1][2]: (birth=0, death)

    dim3 grid(N / 64, N / 64);
    build_d_kernel<<<grid, 256, 0, stream>>>(x, D);
    prim_kernel<<<1, 256, 0, stream>>>(D, out);
}

// Round 4
// 4228.844 us; speedup vs baseline: 1.5144x; 1.1284x over previous
//
#include <hip/hip_runtime.h>
#include <math.h>

// RipsLayer: dim-0 persistence of Rips filtration on 4096 points in R^64.
// Phase 1: dense distance matrix D (64 MiB, in d_ws).
// Phase 2: exact Prim replay, 1 workgroup / 4 waves:
//   - DPP (row_shr/row_bcast) wave min-reduce + ballot index recovery
//     (blocked col ownership -> lowest lane == lowest col, exact ties)
//   - two-phase m1/m2 argmin; tree membership encoded as mind==INF
//   - NEW (vs 4030us baseline): DEFERRED m1. The wave-level m1 key for
//     iteration s+1 is computed at the END of iteration s, inside the
//     row-load flight window (previously dead stall): per-lane argmin of
//     the folded mind = exact 4-op merge of this iter's m1/m2 per-lane
//     argmins (first-index tie-break preserved; proof: argmin of
//     elementwise-min = key-merge of argmins), except the single lane
//     owning the pinned col j, which recomputes its 16-slot tree
//     (predicated; waves without that lane skip via execz). The DPP chain
//     + ballot for the next wave key also run in the flight window. The
//     pre-barrier critical path is now m2 ONLY (one tree + one DPP chain
//     + one ballot fewer than baseline). No speculation, no extra memory
//     ops; selection semantics bit-identical to baseline.

#define N 4096
#define DF 64
#define INF __builtin_huge_valf()
#define INFBITS 0x7f800000u

// ---------------------------------------------------------------------------
// Phase 1: D[i][j] = sqrt(max(|x_i - x_j|^2, 1e-12)), diag = +inf.
// ---------------------------------------------------------------------------
__global__ __launch_bounds__(256) void build_d_kernel(const float* __restrict__ x,
                                                      float* __restrict__ D) {
    __shared__ float As[64][68];
    __shared__ float Bs[64][68];
    const int bi = blockIdx.y * 64;
    const int bj = blockIdx.x * 64;
    const int t = threadIdx.x;

#pragma unroll
    for (int g = 0; g < 4; ++g) {
        int idx = t + 256 * g;
        int row = idx >> 4;
        int k4 = (idx & 15) << 2;
        float4 va = *(const float4*)(x + (size_t)(bi + row) * DF + k4);
        float4 vb = *(const float4*)(x + (size_t)(bj + row) * DF + k4);
        *(float4*)(&As[row][k4]) = va;
        *(float4*)(&Bs[row][k4]) = vb;
    }
    __syncthreads();

    const int ti = (t >> 4) << 2;
    const int tj = (t & 15) << 2;

    float acc[4][4];
#pragma unroll
    for (int r = 0; r < 4; ++r)
#pragma unroll
        for (int c = 0; c < 4; ++c) acc[r][c] = 0.0f;

    for (int k = 0; k < 64; k += 4) {
        float4 a[4], b[4];
#pragma unroll
        for (int r = 0; r < 4; ++r) a[r] = *(const float4*)(&As[ti + r][k]);
#pragma unroll
        for (int c = 0; c < 4; ++c) b[c] = *(const float4*)(&Bs[tj + c][k]);
#pragma unroll
        for (int r = 0; r < 4; ++r)
#pragma unroll
            for (int c = 0; c < 4; ++c) {
                float d0 = a[r].x - b[c].x;
                float d1 = a[r].y - b[c].y;
                float d2 = a[r].z - b[c].z;
                float d3 = a[r].w - b[c].w;
                float s = acc[r][c];
                s = fmaf(d0, d0, s);
                s = fmaf(d1, d1, s);
                s = fmaf(d2, d2, s);
                s = fmaf(d3, d3, s);
                acc[r][c] = s;
            }
    }

#pragma unroll
    for (int r = 0; r < 4; ++r) {
        int i = bi + ti + r;
        float4 v;
        float* vp = &v.x;
#pragma unroll
        for (int c = 0; c < 4; ++c) {
            int j = bj + tj + c;
            vp[c] = (i == j) ? INF : sqrtf(fmaxf(acc[r][c], 1e-12f));
        }
        *(float4*)(D + (size_t)i * N + (bj + tj)) = v;
    }
}

// ---------------------------------------------------------------------------
// Barrier that publishes LDS (lgkmcnt) but leaves global loads in flight.
// ---------------------------------------------------------------------------
__device__ __forceinline__ void barrier_no_drain() {
    __asm__ __volatile__("s_waitcnt lgkmcnt(0)\n\ts_barrier" ::: "memory");
}

// ---------------------------------------------------------------------------
// Wave64 min via DPP: row_shr 1/2/4/8 then row_bcast 15/31; result in lane 63.
// update_dpp(old=INF,...) makes invalid source lanes contribute identity.
// ---------------------------------------------------------------------------
#define DPP_MIN_STEP(x, ctrl)                                                  \
    x = fminf(x, __int_as_float(__builtin_amdgcn_update_dpp(                   \
                     0x7f800000, __float_as_int(x), ctrl, 0xF, 0xF, false)))

__device__ __forceinline__ float wave_min_f32_l63(float x) {
    DPP_MIN_STEP(x, 0x111);  // row_shr:1
    DPP_MIN_STEP(x, 0x112);  // row_shr:2
    DPP_MIN_STEP(x, 0x114);  // row_shr:4
    DPP_MIN_STEP(x, 0x118);  // row_shr:8
    DPP_MIN_STEP(x, 0x142);  // row_bcast:15
    DPP_MIN_STEP(x, 0x143);  // row_bcast:31
    return x;                // lane 63 = wave min
}

// lv/lcol: this lane's local min value and its (lowest) column. Ownership is
// blocked (lane owns cols [16t,16t+16)), so among tied lanes the lowest lane
// holds the lowest column -> exact jnp.argmin first-index semantics.
__device__ __forceinline__ unsigned long long wave_argmin_key(float lv, int lcol) {
    float red = wave_min_f32_l63(lv);
    float wm = __int_as_float(__builtin_amdgcn_readlane(__float_as_int(red), 63));
    unsigned long long tied = __ballot(lv == wm);
    int src = __ffsll(tied) - 1;
    int wcol = __builtin_amdgcn_readlane(lcol, src);
    return ((unsigned long long)__float_as_uint(wm) << 32) | (unsigned)wcol;
}

// Local argmin over 16 values with exact lowest-index tie-break.
__device__ __forceinline__ void local_argmin16(const float* __restrict__ a,
                                               float& bv, int& bi) {
    float v[16];
    int id[16];
#pragma unroll
    for (int i = 0; i < 16; ++i) { v[i] = a[i]; id[i] = i; }
#pragma unroll
    for (int st = 1; st < 16; st <<= 1)
#pragma unroll
        for (int i = 0; i < 16; i += 2 * st)
            if (v[i + st] < v[i]) {  // strict: keep lower index on ties
                v[i] = v[i + st];
                id[i] = id[i + st];
            }
    bv = v[0];
    bi = id[0];
}

// ---------------------------------------------------------------------------
// Phase 2. Invariant: mv[i] == INF  <=>  col (16t+i) is in the tree.
// ---------------------------------------------------------------------------
__global__ __launch_bounds__(256) void prim_kernel(const float* __restrict__ D,
                                                   float* __restrict__ out) {
    __shared__ __align__(16) unsigned long long part[2][4];
    const int t = threadIdx.x;
    const int lane = t & 63;
    const int wv = t >> 6;

    float mv[16];  // mind, pinned INF at tree cols
    float rv[16];  // row of last-selected vertex (in flight across backedge)
    {
        const float4* rp0 = (const float4*)(D + 16 * t);  // row 0; D[0][0]=INF
#pragma unroll
        for (int q = 0; q < 4; ++q) {
            float4 a = rp0[q];
            mv[4 * q + 0] = a.x; mv[4 * q + 1] = a.y;
            mv[4 * q + 2] = a.z; mv[4 * q + 3] = a.w;
        }
#pragma unroll
        for (int i = 0; i < 16; ++i) rv[i] = mv[i];  // "row of vertex 0"
    }

    // Running per-lane argmin over mv and its wave-level key (m1, deferred).
    float bv1;
    int bi1;
    local_argmin16(mv, bv1, bi1);
    unsigned long long key1w = wave_argmin_key(bv1, 16 * t + bi1);

#pragma unroll 1
    for (int s = 1; s < N; ++s) {
        // ---- m2: argmin over the arrived row, tree cols masked to INF ----
        float mr[16];
#pragma unroll
        for (int i = 0; i < 16; ++i)
            mr[i] = (__float_as_uint(mv[i]) == INFBITS) ? INF : rv[i];
        float bv2;
        int bi2;
        local_argmin16(mr, bv2, bi2);
        unsigned long long key2 = wave_argmin_key(bv2, 16 * t + bi2);

        // ---- combine with the precomputed m1 key; exchange across waves ----
        unsigned long long kw = key1w < key2 ? key1w : key2;
        const int pb = s & 1;
        if (lane == 0) part[pb][wv] = kw;
        barrier_no_drain();

        const ulonglong2* pp = (const ulonglong2*)&part[pb][0];
        ulonglong2 ab = pp[0], cd = pp[1];
        unsigned long long b0 = ab.x < ab.y ? ab.x : ab.y;
        unsigned long long b1 = cd.x < cd.y ? cd.x : cd.y;
        unsigned long long best = b0 < b1 ? b0 : b1;
        int j = __builtin_amdgcn_readfirstlane((int)(best & 0xffffffffULL));
        int dbits = __builtin_amdgcn_readfirstlane((int)(best >> 32));

        // ---- issue next row load immediately (consumed next iter in m2) ----
        const float4* rp = (const float4*)(D + (size_t)(unsigned)j * N + 16 * t);
        float4 n0 = rp[0], n1 = rp[1], n2 = rp[2], n3 = rp[3];

        if (t == 0) {
            out[2 * (s - 1)] = 0.0f;
            out[2 * (s - 1) + 1] = __uint_as_float((unsigned)dbits);
        }

        // ---- fold (mind = min(mind, maskedR)) + pin newly-added col j ----
        unsigned jl = (unsigned)j & 15u;
        unsigned jt = (unsigned)j >> 4;
        bool mine = ((unsigned)t == jt);
#pragma unroll
        for (int i = 0; i < 16; ++i) {
            float m = fminf(mv[i], mr[i]);
            mv[i] = (mine && ((unsigned)i == jl)) ? INF : m;
        }

        // ---- deferred m1 for next iter (runs inside the load window) ----
        // argmin(min(mv_old, mr)) == first-index merge of (bv1,bi1),(bv2,bi2);
        // only the lane whose pinned slot was that merged argmin recomputes.
        {
            bool oldwin = (bv1 < bv2) || (bv1 == bv2 && bi1 <= bi2);
            float bvm = oldwin ? bv1 : bv2;
            int bim = oldwin ? bi1 : bi2;
            if (mine && bim == (int)jl) {
                local_argmin16(mv, bvm, bim);  // post-pin recompute (1 lane)
            }
            bv1 = bvm;
            bi1 = bim;
            key1w = wave_argmin_key(bv1, 16 * t + bi1);
        }

        // ---- carry the new row ----
        rv[0] = n0.x;  rv[1] = n0.y;  rv[2] = n0.z;  rv[3] = n0.w;
        rv[4] = n1.x;  rv[5] = n1.y;  rv[6] = n1.z;  rv[7] = n1.w;
        rv[8] = n2.x;  rv[9] = n2.y;  rv[10] = n2.z; rv[11] = n2.w;
        rv[12] = n3.x; rv[13] = n3.y; rv[14] = n3.z; rv[15] = n3.w;
    }
}

// ---------------------------------------------------------------------------
extern "C" void kernel_launch(void* const* d_in, const int* in_sizes, int n_in,
                              void* d_out, int out_size, void* d_ws, size_t ws_size,
                              hipStream_t stream) {
    const float* x = (const float*)d_in[0];
    float* D = (float*)d_ws;     // requires ws_size >= N*N*4 = 64 MiB
    float* out = (float*)d_out;  // [N-1][2]: (birth=0, death)

    dim3 grid(N / 64, N / 64);
    build_d_kernel<<<grid, 256, 0, stream>>>(x, D);
    prim_kernel<<<1, 256, 0, stream>>>(D, out);
}